// Round 4
// baseline (1460.837 us; speedup 1.0000x reference)
//
#include <hip/hip_runtime.h>
#include <stdint.h>

#define NN   8192
#define DIN  256
#define FF   128
#define NF   (NN*FF)          // 1048576
#define SLOPE 0.2f
#define EPSI  1e-5f

typedef float vf4 __attribute__((ext_vector_type(4)));   // native vector for nontemporal builtins

// ---- workspace layout (float offsets) ----
#define OFF_PROJ   0                       // [2][N][F] f32 (k_gemm->k_sprep), then REUSED as bitmask [N][256] u32 (8 MB)
#define OFF_RESID  (2*NF)                  // [N][F] f32
#define OFF_PACKED (3*NF)                  // [N][F] uint32: lo16=bf16(head0), hi16=bf16(head1)
#define OFF_SS     (4*NF)                  // s_src [2][N]
#define OFF_ST     (OFF_SS + 2*NN)         // s_tgt [2][N]
#define OFF_CSUM   (OFF_ST + 2*NN)         // colsum [2][N]
#define OFF_STATS  (OFF_CSUM + 2*NN)       // S, SS (2 floats; padded to 16)
#define OFF_NTAB   (OFF_STATS + 16)        // float4[N] = {st0, st1, rcp_csum0, rcp_csum1}
#define OFF_VALS   (OFF_NTAB + 4*NN)       // [N][F] f32
#define OFF_WT     (OFF_VALS + NF)         // W_res transposed: [DIN][F]
// total = OFF_WT + DIN*FF = 5,357,584 floats ~= 20.5 MiB

__device__ __forceinline__ float lrelu(float x) { return x >= 0.f ? x : SLOPE * x; }

__device__ __forceinline__ uint32_t bfpack(float a, float b) {
  uint32_t ua = __float_as_uint(a); ua += 0x7fffu + ((ua >> 16) & 1u);
  uint32_t ub = __float_as_uint(b); ub += 0x7fffu + ((ub >> 16) & 1u);
  return (ua >> 16) | (ub & 0xffff0000u);
}

// ---- K0: transpose W_res [F][DIN] -> Wt [DIN][F] ----
__global__ __launch_bounds__(256) void k_wt(const float* __restrict__ wres, float* __restrict__ wt) {
  int i = blockIdx.x * 256 + threadIdx.x;
  int d = i >> 7, f = i & 127;
  wt[i] = wres[f * DIN + d];
}

// ---- K1: 3 GEMMs M=8192 K=256 N=128 (heads 0,1 -> proj; y==2 -> resid) ----
__global__ __launch_bounds__(256) void k_gemm(const float* __restrict__ x, const float* __restrict__ Wh,
                                              const float* __restrict__ wt, float* __restrict__ proj,
                                              float* __restrict__ resid) {
  const int h = blockIdx.y;
  const float* __restrict__ Wsrc = (h < 2) ? (Wh + h * (DIN * FF)) : wt;
  float* __restrict__ outp = (h < 2) ? (proj + h * NF) : resid;
  const int row0 = blockIdx.x * 64;
  __shared__ float xs[64 * 68];
  const int tid = threadIdx.x;
  const int ft = tid & 15, rt = tid >> 4;
  const int f0 = ft * 8, r0 = rt * 4;
  float acc[4][8];
#pragma unroll
  for (int j = 0; j < 4; ++j)
#pragma unroll
    for (int k = 0; k < 8; ++k) acc[j][k] = 0.f;

  for (int kc = 0; kc < 4; ++kc) {
    const int d0 = kc * 64;
#pragma unroll
    for (int k2 = 0; k2 < 4; ++k2) {
      int i = tid * 4 + k2 * 1024;
      int r = i >> 6, dd = i & 63;
      *(float4*)&xs[r * 68 + dd] = *(const float4*)&x[(row0 + r) * DIN + d0 + dd];
    }
    __syncthreads();
#pragma unroll
    for (int g = 0; g < 16; ++g) {
      const int dd = g * 4;
      float xr[4][4];
#pragma unroll
      for (int j = 0; j < 4; ++j) {
        float4 t = *(const float4*)&xs[(r0 + j) * 68 + dd];
        xr[j][0] = t.x; xr[j][1] = t.y; xr[j][2] = t.z; xr[j][3] = t.w;
      }
#pragma unroll
      for (int i = 0; i < 4; ++i) {
        float4 wa = *(const float4*)&Wsrc[(d0 + dd + i) * FF + f0];
        float4 wb = *(const float4*)&Wsrc[(d0 + dd + i) * FF + f0 + 4];
#pragma unroll
        for (int j = 0; j < 4; ++j) {
          float xx = xr[j][i];
          acc[j][0] += xx * wa.x; acc[j][1] += xx * wa.y; acc[j][2] += xx * wa.z; acc[j][3] += xx * wa.w;
          acc[j][4] += xx * wb.x; acc[j][5] += xx * wb.y; acc[j][6] += xx * wb.z; acc[j][7] += xx * wb.w;
        }
      }
    }
    __syncthreads();
  }
#pragma unroll
  for (int j = 0; j < 4; ++j) {
    int row = row0 + r0 + j;
    *(float4*)&outp[row * FF + f0]     = make_float4(acc[j][0], acc[j][1], acc[j][2], acc[j][3]);
    *(float4*)&outp[row * FF + f0 + 4] = make_float4(acc[j][4], acc[j][5], acc[j][6], acc[j][7]);
  }
}

// ---- K1b: per-node dots s_src/s_tgt (both heads) + bf16 pack of proj ----
__global__ __launch_bounds__(256) void k_sprep(const float* __restrict__ proj, const float* __restrict__ a_src,
                                               const float* __restrict__ a_tgt, float* __restrict__ ss,
                                               float* __restrict__ st, uint32_t* __restrict__ packed) {
  int lane = threadIdx.x & 63, wid = threadIdx.x >> 6;
  int n = blockIdx.x * 4 + wid;
  float2 q0 = *(const float2*)&proj[n * FF + 2 * lane];
  float2 q1 = *(const float2*)&proj[NF + n * FF + 2 * lane];
  float2 as0 = *(const float2*)&a_src[2 * lane];
  float2 at0 = *(const float2*)&a_tgt[2 * lane];
  float2 as1 = *(const float2*)&a_src[FF + 2 * lane];
  float2 at1 = *(const float2*)&a_tgt[FF + 2 * lane];
  float v0 = q0.x * as0.x + q0.y * as0.y;
  float v1 = q0.x * at0.x + q0.y * at0.y;
  float v2 = q1.x * as1.x + q1.y * as1.y;
  float v3 = q1.x * at1.x + q1.y * at1.y;
#pragma unroll
  for (int o = 1; o < 64; o <<= 1) {
    v0 += __shfl_xor(v0, o); v1 += __shfl_xor(v1, o);
    v2 += __shfl_xor(v2, o); v3 += __shfl_xor(v3, o);
  }
  uint2 pk;
  pk.x = bfpack(q0.x, q1.x);
  pk.y = bfpack(q0.y, q1.y);
  *(uint2*)&packed[n * FF + 2 * lane] = pk;
  if (lane == 0) { ss[n] = v0; ss[NN + n] = v2; st[n] = v1; st[NN + n] = v3; }
}

// ---- K2 v2 (k_scan): wave-per-row single pass over mask:
//   (a) copy mask -> out1 (nontemporal), (b) emit row bitmask (interleaved ballot order),
//   (c) colsum via predicated per-edge atomics.
// Bitmask layout: word widx in [0,256) of row m: c=widx>>3, j=(widx>>1)&3, half=widx&1;
// bit b  ->  column n = c*256 + 128*half + 4*b + j.
__global__ __launch_bounds__(256) void k_scan(const float* __restrict__ mask, float* __restrict__ maskout,
                                              const float* __restrict__ ss, const float* __restrict__ st,
                                              float* __restrict__ csum, uint32_t* __restrict__ bitmask) {
  const int lane = threadIdx.x & 63, wid = threadIdx.x >> 6;
  const int m = blockIdx.x * 4 + wid;
  const float ss0 = ss[m], ss1 = ss[NN + m];
  const vf4* __restrict__ mrow = (const vf4*)(mask + (size_t)m * NN);
  vf4* __restrict__ orow = (vf4*)(maskout + (size_t)m * NN);
  uint32_t* __restrict__ brow = bitmask + m * 256;

  for (int c = 0; c < 32; ++c) {
    vf4 v = __builtin_nontemporal_load(&mrow[c * 64 + lane]);
    __builtin_nontemporal_store(v, &orow[c * 64 + lane]);
    float vv[4] = {v.x, v.y, v.z, v.w};
    unsigned long long bms[4];
#pragma unroll
    for (int j = 0; j < 4; ++j) {
      bool e = vv[j] > -0.5e9f;
      bms[j] = __ballot(e);
      if (e) {
        int n = c * 256 + lane * 4 + j;
        float w0 = __expf(lrelu(ss0 + st[n]));
        float w1 = __expf(lrelu(ss1 + st[NN + n]));
        atomicAdd(&csum[n], w0);
        atomicAdd(&csum[NN + n], w1);
      }
    }
    // assemble 8 words (lane<8 stores word lane): j=lane>>1, half=lane&1
    if (lane < 8) {
      unsigned long long b = bms[lane >> 1];
      brow[c * 8 + lane] = (uint32_t)(b >> ((lane & 1) * 32));
    }
  }
}

// ---- K2c: pack per-column table {st0, st1, 1/csum0, 1/csum1} ----
__global__ __launch_bounds__(256) void k_ntab(const float* __restrict__ st, const float* __restrict__ csum,
                                              float4* __restrict__ ntab) {
  int i = blockIdx.x * 256 + threadIdx.x;
  ntab[i] = make_float4(st[i], st[NN + i], 1.f / csum[i], 1.f / csum[NN + i]);
}

// ---- K3 v3: wave-per-row, bitmask-driven. Phase 1: decode 1KB bitmask -> LDS edge list.
// Phase 2: 64-edge tiles, parallel weight calc, then readlane-broadcast gather (no LDS,
// no mask traffic; `packed` stays L2-resident). ----
__global__ __launch_bounds__(256) void k_vals(const uint32_t* __restrict__ bitmask, const uint32_t* __restrict__ packed,
                                              const float4* __restrict__ ntab, const float* __restrict__ ss,
                                              float* __restrict__ vals, float* __restrict__ stats) {
  __shared__ uint16_t el[4][1024];
  const int lane = threadIdx.x & 63, wid = threadIdx.x >> 6;
  const int m = blockIdx.x * 4 + wid;

  // ---- phase 1: decode bitmask row m ----
  uint4 wv = ((const uint4*)(bitmask + m * 256))[lane];   // words 4*lane..4*lane+3
  uint32_t wd[4] = {wv.x, wv.y, wv.z, wv.w};
  int cnt = __popc(wd[0]) + __popc(wd[1]) + __popc(wd[2]) + __popc(wd[3]);
  int pre = cnt;
#pragma unroll
  for (int o = 1; o < 64; o <<= 1) { int t = __shfl_up(pre, o); if (lane >= o) pre += t; }
  int nE = __shfl(pre, 63);
  int base = pre - cnt;
#pragma unroll
  for (int u = 0; u < 4; ++u) {
    uint32_t w = wd[u];
    int widx = 4 * lane + u;
    int nbase = (widx >> 3) * 256 + (widx & 1) * 128 + ((widx >> 1) & 3);
    while (w) {
      int b = __builtin_ctz(w); w &= w - 1;
      if (base < 1024) el[wid][base] = (uint16_t)(nbase + 4 * b);
      ++base;
    }
  }
  if (nE > 1024) nE = 1024;
  __builtin_amdgcn_wave_barrier();

  // ---- phase 2: tiled gather with register broadcast ----
  const float ss0 = ss[m], ss1 = ss[NN + m];
  float a00 = 0.f, a01 = 0.f, a10 = 0.f, a11 = 0.f;
  const char* __restrict__ pb = (const char*)packed;
  for (int t = 0; t < nE; t += 64) {
    int e = t + lane;
    float w0 = 0.f, w1 = 0.f; uint32_t off = 0;
    if (e < nE) {
      int n = el[wid][e];
      float4 tb = ntab[n];
      w0 = __expf(lrelu(ss0 + tb.x)) * tb.z;
      w1 = __expf(lrelu(ss1 + tb.y)) * tb.w;
      off = (uint32_t)n << 9;
    }
#pragma unroll
    for (int k = 0; k < 64; ++k) {
      float sw0 = __uint_as_float(__builtin_amdgcn_readlane(__float_as_uint(w0), k));
      float sw1 = __uint_as_float(__builtin_amdgcn_readlane(__float_as_uint(w1), k));
      uint32_t so = __builtin_amdgcn_readlane(off, k);
      const uint32_t* __restrict__ p = (const uint32_t*)(pb + so) + lane;
      uint32_t p0 = p[0];
      uint32_t p1 = p[64];
      a00 += sw0 * __uint_as_float(p0 << 16);
      a10 += sw1 * __uint_as_float(p0 & 0xffff0000u);
      a01 += sw0 * __uint_as_float(p1 << 16);
      a11 += sw1 * __uint_as_float(p1 & 0xffff0000u);
    }
  }

  float v0 = 0.5f * (a00 + a10), v1 = 0.5f * (a01 + a11);
  vals[m * FF + lane]      = v0;
  vals[m * FF + 64 + lane] = v1;
  float s = v0 + v1, q = v0 * v0 + v1 * v1;
#pragma unroll
  for (int o = 1; o < 64; o <<= 1) { s += __shfl_xor(s, o); q += __shfl_xor(q, o); }
  if (lane == 0) { atomicAdd(stats, s); atomicAdd(stats + 1, q); }
}

// ---- K5: instance-norm + residual + ELU ----
__global__ __launch_bounds__(256) void k_final(const float* __restrict__ vals, const float* __restrict__ resid,
                                               const float* __restrict__ stats, float* __restrict__ out) {
  int i = (blockIdx.x * 256 + threadIdx.x) * 4;
  float mu = stats[0] * (1.f / NF);
  float var = stats[1] * (1.f / NF) - mu * mu;
  float rs = rsqrtf(var + EPSI);
  float4 v = *(const float4*)&vals[i];
  float4 r = *(const float4*)&resid[i];
  float t0 = (v.x - mu) * rs + r.x;
  float t1 = (v.y - mu) * rs + r.y;
  float t2 = (v.z - mu) * rs + r.z;
  float t3 = (v.w - mu) * rs + r.w;
  float4 o;
  o.x = t0 > 0.f ? t0 : expm1f(t0);
  o.y = t1 > 0.f ? t1 : expm1f(t1);
  o.z = t2 > 0.f ? t2 : expm1f(t2);
  o.w = t3 > 0.f ? t3 : expm1f(t3);
  *(float4*)&out[i] = o;
}

extern "C" void kernel_launch(void* const* d_in, const int* in_sizes, int n_in,
                              void* d_out, int out_size, void* d_ws, size_t ws_size,
                              hipStream_t stream) {
  const float* x     = (const float*)d_in[0];
  const float* mask  = (const float*)d_in[1];
  const float* W     = (const float*)d_in[2];
  const float* a_src = (const float*)d_in[3];
  const float* a_tgt = (const float*)d_in[4];
  const float* wres  = (const float*)d_in[5];
  float* out = (float*)d_out;
  float* wsf = (float*)d_ws;

  float*    proj    = wsf + OFF_PROJ;
  uint32_t* bitmask = (uint32_t*)(wsf + OFF_PROJ);   // overlays proj after k_sprep
  float*    resid   = wsf + OFF_RESID;
  uint32_t* packed  = (uint32_t*)(wsf + OFF_PACKED);
  float*    ss      = wsf + OFF_SS;
  float*    st      = wsf + OFF_ST;
  float*    csum    = wsf + OFF_CSUM;
  float*    stats   = wsf + OFF_STATS;
  float4*   ntab    = (float4*)(wsf + OFF_NTAB);
  float*    vals    = wsf + OFF_VALS;
  float*    wt      = wsf + OFF_WT;

  (void)hipMemsetAsync(csum, 0, (2 * NN + 16) * sizeof(float), stream);

  hipLaunchKernelGGL(k_wt,    dim3(DIN * FF / 256), dim3(256), 0, stream, wres, wt);
  hipLaunchKernelGGL(k_gemm,  dim3(NN / 64, 3),     dim3(256), 0, stream, x, W, wt, proj, resid);
  hipLaunchKernelGGL(k_sprep, dim3(NN / 4),         dim3(256), 0, stream, proj, a_src, a_tgt, ss, st, packed);
  hipLaunchKernelGGL(k_scan,  dim3(NN / 4),         dim3(256), 0, stream, mask, out + NF, ss, st, csum, bitmask);
  hipLaunchKernelGGL(k_ntab,  dim3(NN / 256),       dim3(256), 0, stream, st, csum, ntab);
  hipLaunchKernelGGL(k_vals,  dim3(NN / 4),         dim3(256), 0, stream, bitmask, packed, ntab, ss, vals, stats);
  hipLaunchKernelGGL(k_final, dim3(NF / 1024),      dim3(256), 0, stream, vals, resid, stats, out);
}

// Round 5
// 838.726 us; speedup vs baseline: 1.7417x; 1.7417x over previous
//
#include <hip/hip_runtime.h>
#include <stdint.h>

#define NN   8192
#define DIN  256
#define FF   128
#define NF   (NN*FF)          // 1048576
#define SLOPE 0.2f
#define EPSI  1e-5f

typedef float vf4 __attribute__((ext_vector_type(4)));

// ---- workspace layout (float offsets) ----
#define OFF_PROJ   0                       // [2][N][F] f32 (k_gemm->k_sprep), then REUSED as bitmask [N][256] u32 (8 MB)
#define OFF_RESID  (2*NF)                  // [N][F] f32
#define OFF_PACKED (3*NF)                  // [N][F] uint32: lo16=bf16(head0), hi16=bf16(head1)
#define OFF_SS     (4*NF)                  // s_src [2][N]
#define OFF_ST     (OFF_SS + 2*NN)         // s_tgt [2][N]
#define OFF_CSUM   (OFF_ST + 2*NN)         // colsum [2][N]
#define OFF_STATS  (OFF_CSUM + 2*NN)       // S, SS (2 floats; padded to 16)
#define OFF_NTAB   (OFF_STATS + 16)        // float4[N] = {st0, st1, rcp_csum0, rcp_csum1}
#define OFF_VALS   (OFF_NTAB + 4*NN)       // [N][F] f32
#define OFF_WT     (OFF_VALS + NF)         // W_res transposed: [DIN][F]
// total = OFF_WT + DIN*FF = 5,357,584 floats ~= 20.5 MiB

__device__ __forceinline__ float lrelu(float x) { return x >= 0.f ? x : SLOPE * x; }

__device__ __forceinline__ uint32_t bfpack(float a, float b) {
  uint32_t ua = __float_as_uint(a); ua += 0x7fffu + ((ua >> 16) & 1u);
  uint32_t ub = __float_as_uint(b); ub += 0x7fffu + ((ub >> 16) & 1u);
  return (ua >> 16) | (ub & 0xffff0000u);
}

// ---- K0: transpose W_res [F][DIN] -> Wt [DIN][F] ----
__global__ __launch_bounds__(256) void k_wt(const float* __restrict__ wres, float* __restrict__ wt) {
  int i = blockIdx.x * 256 + threadIdx.x;
  int d = i >> 7, f = i & 127;
  wt[i] = wres[f * DIN + d];
}

// ---- K1: 3 GEMMs M=8192 K=256 N=128 (heads 0,1 -> proj; y==2 -> resid) ----
__global__ __launch_bounds__(256) void k_gemm(const float* __restrict__ x, const float* __restrict__ Wh,
                                              const float* __restrict__ wt, float* __restrict__ proj,
                                              float* __restrict__ resid) {
  const int h = blockIdx.y;
  const float* __restrict__ Wsrc = (h < 2) ? (Wh + h * (DIN * FF)) : wt;
  float* __restrict__ outp = (h < 2) ? (proj + h * NF) : resid;
  const int row0 = blockIdx.x * 64;
  __shared__ float xs[64 * 68];
  const int tid = threadIdx.x;
  const int ft = tid & 15, rt = tid >> 4;
  const int f0 = ft * 8, r0 = rt * 4;
  float acc[4][8];
#pragma unroll
  for (int j = 0; j < 4; ++j)
#pragma unroll
    for (int k = 0; k < 8; ++k) acc[j][k] = 0.f;

  for (int kc = 0; kc < 4; ++kc) {
    const int d0 = kc * 64;
#pragma unroll
    for (int k2 = 0; k2 < 4; ++k2) {
      int i = tid * 4 + k2 * 1024;
      int r = i >> 6, dd = i & 63;
      *(float4*)&xs[r * 68 + dd] = *(const float4*)&x[(row0 + r) * DIN + d0 + dd];
    }
    __syncthreads();
#pragma unroll
    for (int g = 0; g < 16; ++g) {
      const int dd = g * 4;
      float xr[4][4];
#pragma unroll
      for (int j = 0; j < 4; ++j) {
        float4 t = *(const float4*)&xs[(r0 + j) * 68 + dd];
        xr[j][0] = t.x; xr[j][1] = t.y; xr[j][2] = t.z; xr[j][3] = t.w;
      }
#pragma unroll
      for (int i = 0; i < 4; ++i) {
        float4 wa = *(const float4*)&Wsrc[(d0 + dd + i) * FF + f0];
        float4 wb = *(const float4*)&Wsrc[(d0 + dd + i) * FF + f0 + 4];
#pragma unroll
        for (int j = 0; j < 4; ++j) {
          float xx = xr[j][i];
          acc[j][0] += xx * wa.x; acc[j][1] += xx * wa.y; acc[j][2] += xx * wa.z; acc[j][3] += xx * wa.w;
          acc[j][4] += xx * wb.x; acc[j][5] += xx * wb.y; acc[j][6] += xx * wb.z; acc[j][7] += xx * wb.w;
        }
      }
    }
    __syncthreads();
  }
#pragma unroll
  for (int j = 0; j < 4; ++j) {
    int row = row0 + r0 + j;
    *(float4*)&outp[row * FF + f0]     = make_float4(acc[j][0], acc[j][1], acc[j][2], acc[j][3]);
    *(float4*)&outp[row * FF + f0 + 4] = make_float4(acc[j][4], acc[j][5], acc[j][6], acc[j][7]);
  }
}

// ---- K1b: per-node dots s_src/s_tgt (both heads) + bf16 pack of proj ----
__global__ __launch_bounds__(256) void k_sprep(const float* __restrict__ proj, const float* __restrict__ a_src,
                                               const float* __restrict__ a_tgt, float* __restrict__ ss,
                                               float* __restrict__ st, uint32_t* __restrict__ packed) {
  int lane = threadIdx.x & 63, wid = threadIdx.x >> 6;
  int n = blockIdx.x * 4 + wid;
  float2 q0 = *(const float2*)&proj[n * FF + 2 * lane];
  float2 q1 = *(const float2*)&proj[NF + n * FF + 2 * lane];
  float2 as0 = *(const float2*)&a_src[2 * lane];
  float2 at0 = *(const float2*)&a_tgt[2 * lane];
  float2 as1 = *(const float2*)&a_src[FF + 2 * lane];
  float2 at1 = *(const float2*)&a_tgt[FF + 2 * lane];
  float v0 = q0.x * as0.x + q0.y * as0.y;
  float v1 = q0.x * at0.x + q0.y * at0.y;
  float v2 = q1.x * as1.x + q1.y * as1.y;
  float v3 = q1.x * at1.x + q1.y * at1.y;
#pragma unroll
  for (int o = 1; o < 64; o <<= 1) {
    v0 += __shfl_xor(v0, o); v1 += __shfl_xor(v1, o);
    v2 += __shfl_xor(v2, o); v3 += __shfl_xor(v3, o);
  }
  uint2 pk;
  pk.x = bfpack(q0.x, q1.x);
  pk.y = bfpack(q0.y, q1.y);
  *(uint2*)&packed[n * FF + 2 * lane] = pk;
  if (lane == 0) { ss[n] = v0; ss[NN + n] = v2; st[n] = v1; st[NN + n] = v3; }
}

// ---- K2 v3 (k_scan): column-stripe blocks; single mask pass:
//   (a) copy mask -> out1 (nontemporal), (b) emit bitmask word = m*256 + n/32, bit = n&31,
//   (c) colsum in REGISTERS over 256 rows, 2 atomics per thread at the end.
__global__ __launch_bounds__(256) void k_scan(const float* __restrict__ mask, float* __restrict__ maskout,
                                              const float* __restrict__ ss, const float* __restrict__ st,
                                              float* __restrict__ csum, uint32_t* __restrict__ bitmask) {
  const int tid = threadIdx.x;
  const int lane = tid & 63, wv = tid >> 6;
  const int n = blockIdx.x * 256 + tid;
  const int m0 = blockIdx.y * 256;
  const int wbase = blockIdx.x * 8 + wv * 2;     // word pair index within a row
  const float st0 = st[n], st1 = st[NN + n];
  float c0 = 0.f, c1 = 0.f;

  for (int i = 0; i < 256; ++i) {
    const int m = m0 + i;
    const size_t idx = (size_t)m * NN + n;
    float v = __builtin_nontemporal_load(&mask[idx]);
    __builtin_nontemporal_store(v, &maskout[idx]);
    bool e = v > -0.5e9f;                        // edges exactly 0.0f, non-edges -1e9
    unsigned long long bm = __ballot(e);
    if (lane == 0) {
      uint2 w2 = make_uint2((uint32_t)bm, (uint32_t)(bm >> 32));
      *(uint2*)&bitmask[m * 256 + wbase] = w2;
    }
    float w0 = __expf(lrelu(ss[m] + st0));
    float w1 = __expf(lrelu(ss[NN + m] + st1));
    c0 += e ? w0 : 0.f;
    c1 += e ? w1 : 0.f;
  }
  atomicAdd(&csum[n], c0);
  atomicAdd(&csum[NN + n], c1);
}

// ---- K2c: pack per-column table {st0, st1, 1/csum0, 1/csum1} ----
__global__ __launch_bounds__(256) void k_ntab(const float* __restrict__ st, const float* __restrict__ csum,
                                              float4* __restrict__ ntab) {
  int i = blockIdx.x * 256 + threadIdx.x;
  ntab[i] = make_float4(st[i], st[NN + i], 1.f / csum[i], 1.f / csum[NN + i]);
}

// ---- K3 v4: wave-per-row, bitmask-driven (word = m*256 + n/32, bit = n&31 -> sorted list).
// Phase 1: decode 1KB bitmask -> LDS edge list. Phase 2: 64-edge tiles, parallel weight
// calc, readlane-broadcast gather (no LDS in inner loop; `packed` stays L2-resident). ----
__global__ __launch_bounds__(256) void k_vals(const uint32_t* __restrict__ bitmask, const uint32_t* __restrict__ packed,
                                              const float4* __restrict__ ntab, const float* __restrict__ ss,
                                              float* __restrict__ vals, float* __restrict__ stats) {
  __shared__ uint16_t el[4][1024];
  const int lane = threadIdx.x & 63, wid = threadIdx.x >> 6;
  const int m = blockIdx.x * 4 + wid;

  // ---- phase 1: decode bitmask row m (sorted columns) ----
  uint4 wv = ((const uint4*)(bitmask + m * 256))[lane];   // words 4*lane..4*lane+3 -> cols [128*lane, 128*lane+128)
  uint32_t wd[4] = {wv.x, wv.y, wv.z, wv.w};
  int cnt = __popc(wd[0]) + __popc(wd[1]) + __popc(wd[2]) + __popc(wd[3]);
  int pre = cnt;
#pragma unroll
  for (int o = 1; o < 64; o <<= 1) { int t = __shfl_up(pre, o); if (lane >= o) pre += t; }
  int nE = __shfl(pre, 63);
  int base = pre - cnt;
#pragma unroll
  for (int u = 0; u < 4; ++u) {
    uint32_t w = wd[u];
    int nbase = lane * 128 + u * 32;
    while (w) {
      int b = __builtin_ctz(w); w &= w - 1;
      if (base < 1024) el[wid][base] = (uint16_t)(nbase + b);
      ++base;
    }
  }
  if (nE > 1024) nE = 1024;
  __builtin_amdgcn_wave_barrier();

  // ---- phase 2: tiled gather with register broadcast ----
  const float ss0 = ss[m], ss1 = ss[NN + m];
  float a00 = 0.f, a01 = 0.f, a10 = 0.f, a11 = 0.f;
  const char* __restrict__ pb = (const char*)packed;
  for (int t = 0; t < nE; t += 64) {
    int e = t + lane;
    float w0 = 0.f, w1 = 0.f; uint32_t off = 0;
    if (e < nE) {
      int n = el[wid][e];
      float4 tb = ntab[n];
      w0 = __expf(lrelu(ss0 + tb.x)) * tb.z;
      w1 = __expf(lrelu(ss1 + tb.y)) * tb.w;
      off = (uint32_t)n << 9;
    }
#pragma unroll
    for (int k = 0; k < 64; ++k) {
      float sw0 = __uint_as_float(__builtin_amdgcn_readlane(__float_as_uint(w0), k));
      float sw1 = __uint_as_float(__builtin_amdgcn_readlane(__float_as_uint(w1), k));
      uint32_t so = __builtin_amdgcn_readlane(off, k);
      const uint32_t* __restrict__ p = (const uint32_t*)(pb + so) + lane;
      uint32_t p0 = p[0];
      uint32_t p1 = p[64];
      a00 += sw0 * __uint_as_float(p0 << 16);
      a10 += sw1 * __uint_as_float(p0 & 0xffff0000u);
      a01 += sw0 * __uint_as_float(p1 << 16);
      a11 += sw1 * __uint_as_float(p1 & 0xffff0000u);
    }
  }

  float v0 = 0.5f * (a00 + a10), v1 = 0.5f * (a01 + a11);
  vals[m * FF + lane]      = v0;
  vals[m * FF + 64 + lane] = v1;
  float s = v0 + v1, q = v0 * v0 + v1 * v1;
#pragma unroll
  for (int o = 1; o < 64; o <<= 1) { s += __shfl_xor(s, o); q += __shfl_xor(q, o); }
  if (lane == 0) { atomicAdd(stats, s); atomicAdd(stats + 1, q); }
}

// ---- K5: instance-norm + residual + ELU ----
__global__ __launch_bounds__(256) void k_final(const float* __restrict__ vals, const float* __restrict__ resid,
                                               const float* __restrict__ stats, float* __restrict__ out) {
  int i = (blockIdx.x * 256 + threadIdx.x) * 4;
  float mu = stats[0] * (1.f / NF);
  float var = stats[1] * (1.f / NF) - mu * mu;
  float rs = rsqrtf(var + EPSI);
  float4 v = *(const float4*)&vals[i];
  float4 r = *(const float4*)&resid[i];
  float t0 = (v.x - mu) * rs + r.x;
  float t1 = (v.y - mu) * rs + r.y;
  float t2 = (v.z - mu) * rs + r.z;
  float t3 = (v.w - mu) * rs + r.w;
  float4 o;
  o.x = t0 > 0.f ? t0 : expm1f(t0);
  o.y = t1 > 0.f ? t1 : expm1f(t1);
  o.z = t2 > 0.f ? t2 : expm1f(t2);
  o.w = t3 > 0.f ? t3 : expm1f(t3);
  *(float4*)&out[i] = o;
}

extern "C" void kernel_launch(void* const* d_in, const int* in_sizes, int n_in,
                              void* d_out, int out_size, void* d_ws, size_t ws_size,
                              hipStream_t stream) {
  const float* x     = (const float*)d_in[0];
  const float* mask  = (const float*)d_in[1];
  const float* W     = (const float*)d_in[2];
  const float* a_src = (const float*)d_in[3];
  const float* a_tgt = (const float*)d_in[4];
  const float* wres  = (const float*)d_in[5];
  float* out = (float*)d_out;
  float* wsf = (float*)d_ws;

  float*    proj    = wsf + OFF_PROJ;
  uint32_t* bitmask = (uint32_t*)(wsf + OFF_PROJ);   // overlays proj after k_sprep
  float*    resid   = wsf + OFF_RESID;
  uint32_t* packed  = (uint32_t*)(wsf + OFF_PACKED);
  float*    ss      = wsf + OFF_SS;
  float*    st      = wsf + OFF_ST;
  float*    csum    = wsf + OFF_CSUM;
  float*    stats   = wsf + OFF_STATS;
  float4*   ntab    = (float4*)(wsf + OFF_NTAB);
  float*    vals    = wsf + OFF_VALS;
  float*    wt      = wsf + OFF_WT;

  (void)hipMemsetAsync(csum, 0, (2 * NN + 16) * sizeof(float), stream);

  hipLaunchKernelGGL(k_wt,    dim3(DIN * FF / 256), dim3(256), 0, stream, wres, wt);
  hipLaunchKernelGGL(k_gemm,  dim3(NN / 64, 3),     dim3(256), 0, stream, x, W, wt, proj, resid);
  hipLaunchKernelGGL(k_sprep, dim3(NN / 4),         dim3(256), 0, stream, proj, a_src, a_tgt, ss, st, packed);
  hipLaunchKernelGGL(k_scan,  dim3(NN / 256, NN / 256), dim3(256), 0, stream, mask, out + NF, ss, st, csum, bitmask);
  hipLaunchKernelGGL(k_ntab,  dim3(NN / 256),       dim3(256), 0, stream, st, csum, ntab);
  hipLaunchKernelGGL(k_vals,  dim3(NN / 4),         dim3(256), 0, stream, bitmask, packed, ntab, ss, vals, stats);
  hipLaunchKernelGGL(k_final, dim3(NF / 1024),      dim3(256), 0, stream, vals, resid, stats, out);
}

// Round 6
// 769.162 us; speedup vs baseline: 1.8993x; 1.0904x over previous
//
#include <hip/hip_runtime.h>
#include <stdint.h>

#define NN   8192
#define DIN  256
#define FF   128
#define NF   (NN*FF)          // 1048576
#define SLOPE 0.2f
#define EPSI  1e-5f

typedef float vf4 __attribute__((ext_vector_type(4)));

// ---- workspace layout (float offsets) ----
#define OFF_PROJ   0                       // [2][N][F] f32 (k_gemm->k_sprep), then REUSED as bitmask [N][256] u32 (8 MB)
#define OFF_RESID  (2*NF)                  // [N][F] f32
#define OFF_PACKED (3*NF)                  // [N][F] uint32: lo16=bf16(head0), hi16=bf16(head1)
#define OFF_SS     (4*NF)                  // s_src [2][N]
#define OFF_ST     (OFF_SS + 2*NN)         // s_tgt [2][N]
#define OFF_CSUM   (OFF_ST + 2*NN)         // colsum [2][N]
#define OFF_STATS  (OFF_CSUM + 2*NN)       // S, SS (2 floats; padded to 16)
#define OFF_NTAB   (OFF_STATS + 16)        // float4[N] = {st0, st1, rcp_csum0, rcp_csum1}
#define OFF_VALS   (OFF_NTAB + 4*NN)       // [N][F] f32
#define OFF_WT     (OFF_VALS + NF)         // W_res transposed: [DIN][F]
// total = OFF_WT + DIN*FF = 5,357,584 floats ~= 20.5 MiB

__device__ __forceinline__ float lrelu(float x) { return x >= 0.f ? x : SLOPE * x; }

__device__ __forceinline__ uint32_t bfpack(float a, float b) {
  uint32_t ua = __float_as_uint(a); ua += 0x7fffu + ((ua >> 16) & 1u);
  uint32_t ub = __float_as_uint(b); ub += 0x7fffu + ((ub >> 16) & 1u);
  return (ua >> 16) | (ub & 0xffff0000u);
}

// ---- K0: transpose W_res [F][DIN] -> Wt [DIN][F] ----
__global__ __launch_bounds__(256) void k_wt(const float* __restrict__ wres, float* __restrict__ wt) {
  int i = blockIdx.x * 256 + threadIdx.x;
  int d = i >> 7, f = i & 127;
  wt[i] = wres[f * DIN + d];
}

// ---- K1: 3 GEMMs M=8192 K=256 N=128 (heads 0,1 -> proj; y==2 -> resid) ----
__global__ __launch_bounds__(256) void k_gemm(const float* __restrict__ x, const float* __restrict__ Wh,
                                              const float* __restrict__ wt, float* __restrict__ proj,
                                              float* __restrict__ resid) {
  const int h = blockIdx.y;
  const float* __restrict__ Wsrc = (h < 2) ? (Wh + h * (DIN * FF)) : wt;
  float* __restrict__ outp = (h < 2) ? (proj + h * NF) : resid;
  const int row0 = blockIdx.x * 64;
  __shared__ float xs[64 * 68];
  const int tid = threadIdx.x;
  const int ft = tid & 15, rt = tid >> 4;
  const int f0 = ft * 8, r0 = rt * 4;
  float acc[4][8];
#pragma unroll
  for (int j = 0; j < 4; ++j)
#pragma unroll
    for (int k = 0; k < 8; ++k) acc[j][k] = 0.f;

  for (int kc = 0; kc < 4; ++kc) {
    const int d0 = kc * 64;
#pragma unroll
    for (int k2 = 0; k2 < 4; ++k2) {
      int i = tid * 4 + k2 * 1024;
      int r = i >> 6, dd = i & 63;
      *(float4*)&xs[r * 68 + dd] = *(const float4*)&x[(row0 + r) * DIN + d0 + dd];
    }
    __syncthreads();
#pragma unroll
    for (int g = 0; g < 16; ++g) {
      const int dd = g * 4;
      float xr[4][4];
#pragma unroll
      for (int j = 0; j < 4; ++j) {
        float4 t = *(const float4*)&xs[(r0 + j) * 68 + dd];
        xr[j][0] = t.x; xr[j][1] = t.y; xr[j][2] = t.z; xr[j][3] = t.w;
      }
#pragma unroll
      for (int i = 0; i < 4; ++i) {
        float4 wa = *(const float4*)&Wsrc[(d0 + dd + i) * FF + f0];
        float4 wb = *(const float4*)&Wsrc[(d0 + dd + i) * FF + f0 + 4];
#pragma unroll
        for (int j = 0; j < 4; ++j) {
          float xx = xr[j][i];
          acc[j][0] += xx * wa.x; acc[j][1] += xx * wa.y; acc[j][2] += xx * wa.z; acc[j][3] += xx * wa.w;
          acc[j][4] += xx * wb.x; acc[j][5] += xx * wb.y; acc[j][6] += xx * wb.z; acc[j][7] += xx * wb.w;
        }
      }
    }
    __syncthreads();
  }
#pragma unroll
  for (int j = 0; j < 4; ++j) {
    int row = row0 + r0 + j;
    *(float4*)&outp[row * FF + f0]     = make_float4(acc[j][0], acc[j][1], acc[j][2], acc[j][3]);
    *(float4*)&outp[row * FF + f0 + 4] = make_float4(acc[j][4], acc[j][5], acc[j][6], acc[j][7]);
  }
}

// ---- K1b: per-node dots s_src/s_tgt (both heads) + bf16 pack of proj ----
__global__ __launch_bounds__(256) void k_sprep(const float* __restrict__ proj, const float* __restrict__ a_src,
                                               const float* __restrict__ a_tgt, float* __restrict__ ss,
                                               float* __restrict__ st, uint32_t* __restrict__ packed) {
  int lane = threadIdx.x & 63, wid = threadIdx.x >> 6;
  int n = blockIdx.x * 4 + wid;
  float2 q0 = *(const float2*)&proj[n * FF + 2 * lane];
  float2 q1 = *(const float2*)&proj[NF + n * FF + 2 * lane];
  float2 as0 = *(const float2*)&a_src[2 * lane];
  float2 at0 = *(const float2*)&a_tgt[2 * lane];
  float2 as1 = *(const float2*)&a_src[FF + 2 * lane];
  float2 at1 = *(const float2*)&a_tgt[FF + 2 * lane];
  float v0 = q0.x * as0.x + q0.y * as0.y;
  float v1 = q0.x * at0.x + q0.y * at0.y;
  float v2 = q1.x * as1.x + q1.y * as1.y;
  float v3 = q1.x * at1.x + q1.y * at1.y;
#pragma unroll
  for (int o = 1; o < 64; o <<= 1) {
    v0 += __shfl_xor(v0, o); v1 += __shfl_xor(v1, o);
    v2 += __shfl_xor(v2, o); v3 += __shfl_xor(v3, o);
  }
  uint2 pk;
  pk.x = bfpack(q0.x, q1.x);
  pk.y = bfpack(q0.y, q1.y);
  *(uint2*)&packed[n * FF + 2 * lane] = pk;
  if (lane == 0) { ss[n] = v0; ss[NN + n] = v2; st[n] = v1; st[NN + n] = v3; }
}

// ---- K2 v4 (k_scan): grid (32,64): 256 cols x 128 rows per block; 4-row explicit
// load batches for MLP; bitmask word = m*256 + n/32 (sorted layout, same as r5);
// colsum in registers, 2 atomics/thread (64-way contention). ----
__global__ __launch_bounds__(256) void k_scan(const float* __restrict__ mask, float* __restrict__ maskout,
                                              const float* __restrict__ ss, const float* __restrict__ st,
                                              float* __restrict__ csum, uint32_t* __restrict__ bitmask) {
  const int tid = threadIdx.x;
  const int lane = tid & 63, wv = tid >> 6;
  const int n = blockIdx.x * 256 + tid;
  const int m0 = blockIdx.y * 128;
  const int wbase = blockIdx.x * 8 + wv * 2;     // word-pair index within a row
  const float st0 = st[n], st1 = st[NN + n];
  float c0 = 0.f, c1 = 0.f;

  for (int i = 0; i < 128; i += 4) {
    float v[4];
#pragma unroll
    for (int r = 0; r < 4; ++r)
      v[r] = __builtin_nontemporal_load(&mask[(size_t)(m0 + i + r) * NN + n]);
#pragma unroll
    for (int r = 0; r < 4; ++r) {
      const int m = m0 + i + r;
      __builtin_nontemporal_store(v[r], &maskout[(size_t)m * NN + n]);
      bool e = v[r] > -0.5e9f;                   // edges exactly 0.0f, non-edges -1e9
      unsigned long long bm = __ballot(e);
      if (lane == 0)
        *(uint2*)&bitmask[m * 256 + wbase] = make_uint2((uint32_t)bm, (uint32_t)(bm >> 32));
      float w0 = __expf(lrelu(ss[m] + st0));
      float w1 = __expf(lrelu(ss[NN + m] + st1));
      c0 += e ? w0 : 0.f;
      c1 += e ? w1 : 0.f;
    }
  }
  atomicAdd(&csum[n], c0);
  atomicAdd(&csum[NN + n], c1);
}

// ---- K2c: pack per-column table {st0, st1, 1/csum0, 1/csum1} ----
__global__ __launch_bounds__(256) void k_ntab(const float* __restrict__ st, const float* __restrict__ csum,
                                              float4* __restrict__ ntab) {
  int i = blockIdx.x * 256 + threadIdx.x;
  ntab[i] = make_float4(st[i], st[NN + i], 1.f / csum[i], 1.f / csum[NN + i]);
}

// ---- K3 v5: wave-per-row. Phase 1: decode sorted bitmask -> LDS edge list.
// Phase 2: 64-edge tiles; per-lane weight calc; gather in EXPLICIT 16-edge register
// batches of dwordx2 (1 load/edge, 16 in flight -> latency hidden; lane owns f-pair). ----
__global__ __launch_bounds__(256) void k_vals(const uint32_t* __restrict__ bitmask, const uint32_t* __restrict__ packed,
                                              const float4* __restrict__ ntab, const float* __restrict__ ss,
                                              float* __restrict__ vals, float* __restrict__ stats) {
  __shared__ uint16_t el[4][1024];
  const int lane = threadIdx.x & 63, wid = threadIdx.x >> 6;
  const int m = blockIdx.x * 4 + wid;

  // ---- phase 1: decode bitmask row m (sorted columns) ----
  uint4 wv = ((const uint4*)(bitmask + m * 256))[lane];   // words 4*lane..4*lane+3 -> cols [128*lane, 128*lane+128)
  uint32_t wd[4] = {wv.x, wv.y, wv.z, wv.w};
  int cnt = __popc(wd[0]) + __popc(wd[1]) + __popc(wd[2]) + __popc(wd[3]);
  int pre = cnt;
#pragma unroll
  for (int o = 1; o < 64; o <<= 1) { int t = __shfl_up(pre, o); if (lane >= o) pre += t; }
  int nE = __shfl(pre, 63);
  int base = pre - cnt;
#pragma unroll
  for (int u = 0; u < 4; ++u) {
    uint32_t w = wd[u];
    int nbase = lane * 128 + u * 32;
    while (w) {
      int b = __builtin_ctz(w); w &= w - 1;
      if (base < 1024) el[wid][base] = (uint16_t)(nbase + b);
      ++base;
    }
  }
  if (nE > 1024) nE = 1024;
  __builtin_amdgcn_wave_barrier();

  // ---- phase 2: tiled gather, explicit 16-deep load batches ----
  const float ss0 = ss[m], ss1 = ss[NN + m];
  float a00 = 0.f, a01 = 0.f, a10 = 0.f, a11 = 0.f;   // f=2*lane (h0,h1), f=2*lane+1 (h0,h1)
  const char* __restrict__ pb = (const char*)packed;
  const int lane8 = 8 * lane;
  for (int t = 0; t < nE; t += 64) {
    int e = t + lane;
    float w0 = 0.f, w1 = 0.f; uint32_t off = 0;
    if (e < nE) {
      int n = el[wid][e];
      float4 tb = ntab[n];
      w0 = __expf(lrelu(ss0 + tb.x)) * tb.z;
      w1 = __expf(lrelu(ss1 + tb.y)) * tb.w;
      off = (uint32_t)n << 9;
    }
#pragma unroll 1
    for (int k2 = 0; k2 < 4; ++k2) {
      uint2 d[16];
#pragma unroll
      for (int j = 0; j < 16; ++j) {
        uint32_t so = __builtin_amdgcn_readlane(off, k2 * 16 + j);
        d[j] = *(const uint2*)(pb + so + lane8);
      }
#pragma unroll
      for (int j = 0; j < 16; ++j) {
        float sw0 = __uint_as_float(__builtin_amdgcn_readlane(__float_as_uint(w0), k2 * 16 + j));
        float sw1 = __uint_as_float(__builtin_amdgcn_readlane(__float_as_uint(w1), k2 * 16 + j));
        uint32_t pa = d[j].x, pc = d[j].y;
        a00 += sw0 * __uint_as_float(pa << 16);
        a10 += sw1 * __uint_as_float(pa & 0xffff0000u);
        a01 += sw0 * __uint_as_float(pc << 16);
        a11 += sw1 * __uint_as_float(pc & 0xffff0000u);
      }
    }
  }

  float v0 = 0.5f * (a00 + a10), v1 = 0.5f * (a01 + a11);
  *(float2*)&vals[m * FF + 2 * lane] = make_float2(v0, v1);
  float s = v0 + v1, q = v0 * v0 + v1 * v1;
#pragma unroll
  for (int o = 1; o < 64; o <<= 1) { s += __shfl_xor(s, o); q += __shfl_xor(q, o); }
  if (lane == 0) { atomicAdd(stats, s); atomicAdd(stats + 1, q); }
}

// ---- K5: instance-norm + residual + ELU ----
__global__ __launch_bounds__(256) void k_final(const float* __restrict__ vals, const float* __restrict__ resid,
                                               const float* __restrict__ stats, float* __restrict__ out) {
  int i = (blockIdx.x * 256 + threadIdx.x) * 4;
  float mu = stats[0] * (1.f / NF);
  float var = stats[1] * (1.f / NF) - mu * mu;
  float rs = rsqrtf(var + EPSI);
  float4 v = *(const float4*)&vals[i];
  float4 r = *(const float4*)&resid[i];
  float t0 = (v.x - mu) * rs + r.x;
  float t1 = (v.y - mu) * rs + r.y;
  float t2 = (v.z - mu) * rs + r.z;
  float t3 = (v.w - mu) * rs + r.w;
  float4 o;
  o.x = t0 > 0.f ? t0 : expm1f(t0);
  o.y = t1 > 0.f ? t1 : expm1f(t1);
  o.z = t2 > 0.f ? t2 : expm1f(t2);
  o.w = t3 > 0.f ? t3 : expm1f(t3);
  *(float4*)&out[i] = o;
}

extern "C" void kernel_launch(void* const* d_in, const int* in_sizes, int n_in,
                              void* d_out, int out_size, void* d_ws, size_t ws_size,
                              hipStream_t stream) {
  const float* x     = (const float*)d_in[0];
  const float* mask  = (const float*)d_in[1];
  const float* W     = (const float*)d_in[2];
  const float* a_src = (const float*)d_in[3];
  const float* a_tgt = (const float*)d_in[4];
  const float* wres  = (const float*)d_in[5];
  float* out = (float*)d_out;
  float* wsf = (float*)d_ws;

  float*    proj    = wsf + OFF_PROJ;
  uint32_t* bitmask = (uint32_t*)(wsf + OFF_PROJ);   // overlays proj after k_sprep
  float*    resid   = wsf + OFF_RESID;
  uint32_t* packed  = (uint32_t*)(wsf + OFF_PACKED);
  float*    ss      = wsf + OFF_SS;
  float*    st      = wsf + OFF_ST;
  float*    csum    = wsf + OFF_CSUM;
  float*    stats   = wsf + OFF_STATS;
  float4*   ntab    = (float4*)(wsf + OFF_NTAB);
  float*    vals    = wsf + OFF_VALS;
  float*    wt      = wsf + OFF_WT;

  (void)hipMemsetAsync(csum, 0, (2 * NN + 16) * sizeof(float), stream);

  hipLaunchKernelGGL(k_wt,    dim3(DIN * FF / 256), dim3(256), 0, stream, wres, wt);
  hipLaunchKernelGGL(k_gemm,  dim3(NN / 64, 3),     dim3(256), 0, stream, x, W, wt, proj, resid);
  hipLaunchKernelGGL(k_sprep, dim3(NN / 4),         dim3(256), 0, stream, proj, a_src, a_tgt, ss, st, packed);
  hipLaunchKernelGGL(k_scan,  dim3(NN / 256, NN / 128), dim3(256), 0, stream, mask, out + NF, ss, st, csum, bitmask);
  hipLaunchKernelGGL(k_ntab,  dim3(NN / 256),       dim3(256), 0, stream, st, csum, ntab);
  hipLaunchKernelGGL(k_vals,  dim3(NN / 4),         dim3(256), 0, stream, bitmask, packed, ntab, ss, vals, stats);
  hipLaunchKernelGGL(k_final, dim3(NF / 1024),      dim3(256), 0, stream, vals, resid, stats, out);
}